// Round 12
// baseline (245.549 us; speedup 1.0000x reference)
//
#include <hip/hip_runtime.h>
#include <hip/hip_fp16.h>

// Capsule routing via materialized fp16 u_hat (L3-resident), multi-kernel,
// plain stores only. Ledger: R1 coop grid.sync ~60us -> never. R2 contended
// atomics -> never. R3/R4 occupancy juggling -> regress. R5 XCD swizzle 264.7.
// R8 fp16 split-K 254.7. R9 pk_fma 248.8. R11 materialized-U restructure 216.7.
// R12: (a) gemv-s(it0) folded into ubuild (csm==0.1 exactly at it0, so s0 =
// 0.1*sum_c U computed while U is in registers; 32-slice split-K epilogue) --
// kills one 94MB U pass and one launch; (b) agree takes (s_base,nsl) to reduce
// 32 or 8 slices; (c) gemvs nobij flag for it1 (b1 = agg0, no bij read);
// (d) XCD swizzles on ubuild (cc-siblings share x-slice) and agree (j-siblings
// share s reads). 9 launches, 7 U passes.
// B=256, K_IN=8, C=1152, J=10, D=16, 4 iters. n = j*16+d.

typedef float v2f __attribute__((ext_vector_type(2)));

#define C_IN  1152
#define J_U   10
#define M_DIM 9216
#define N_DIM 160
#define B_SZ  256

// ---- ws layout (float offsets); ws is 256 MiB = 67.1M floats ----
#define OFF_XT  0              // Xt[9216][256] fp32
#define OFF_U   2400000        // U half[160][1152][256] = 23.6M floats of space
#define OFF_SP8 26000000       // s_part fp32 [8][160][256]
#define OFF_SP32 26400000      // s_part fp32 [32][160][256] (it0, from ubuild)
#define OFF_B0  27800000       // bij ping [1152][10]
#define OFF_B1  27820000       // bij pong [1152][10]
#define OFF_AG  27840000       // agg [1152][10] (full, written before read)

// ================= prep: transpose x -> Xt (proven 64x64 tile) =================
__global__ __launch_bounds__(256) void k_prep(const float* __restrict__ x,
                                              float* __restrict__ Xt) {
    __shared__ float T[64][65];
    const int bid = blockIdx.x, t = threadIdx.x;
    const int m0 = (bid % 144) * 64, b0 = (bid / 144) * 64;
    {
        const int b_l = t >> 2, q = t & 3;
        const float* xp = x + (size_t)(b0 + b_l) * M_DIM + m0 + q * 16;
#pragma unroll
        for (int u = 0; u < 4; ++u) {
            const float4 v = *reinterpret_cast<const float4*>(xp + 4 * u);
            T[q * 16 + 4 * u + 0][b_l] = v.x;
            T[q * 16 + 4 * u + 1][b_l] = v.y;
            T[q * 16 + 4 * u + 2][b_l] = v.z;
            T[q * 16 + 4 * u + 3][b_l] = v.w;
        }
    }
    __syncthreads();
    {
        const int m_l = t >> 2, q = t & 3;
        float4* op = reinterpret_cast<float4*>(Xt + (size_t)(m0 + m_l) * B_SZ + b0 + q * 16);
#pragma unroll
        for (int u = 0; u < 4; ++u)
            op[u] = make_float4(T[m_l][q * 16 + 4 * u], T[m_l][q * 16 + 4 * u + 1],
                                T[m_l][q * 16 + 4 * u + 2], T[m_l][q * 16 + 4 * u + 3]);
    }
}

// ===== ubuild: U[n][c][b] = sum_k W[c,n,k]*Xt[k*C+c][b]; also s0 split-K ========
// 512 blocks = 32 c-chunks(36) x 16 n-chunks(10), XCD-swizzled so the 16
// nc-siblings of a cc (sharing a 295KB x-slice) land on one XCD's L2.
// Epilogue: s0[cc][n][b] = 0.1 * sum over the block's 36 c (csm==0.1 at it0).
__global__ __launch_bounds__(256) void k_ubuild(const float* __restrict__ Xt,
                                                const float* __restrict__ W,
                                                __half2* __restrict__ U2,
                                                float* __restrict__ s32) {
    __shared__ float Wl[2880];                 // [36 c][10 n][8 k]
    __shared__ v2f Sred[2][10][128];
    const int vb = (blockIdx.x & 7) * 64 + (blockIdx.x >> 3);  // XCD swizzle (512=8x64)
    const int cc = vb >> 4, nc = vb & 15;
    const int c0 = cc * 36, n0 = nc * 10;
    const int t = threadIdx.x;
    const float4* W4 = reinterpret_cast<const float4*>(W);
    float4* Wl4 = reinterpret_cast<float4*>(Wl);
    for (int i = t; i < 720; i += 256) {       // 36 c x 10 n x 2 float4
        const int c = i / 20, r = i - c * 20;
        const int n = r >> 1, half = r & 1;
        Wl4[i] = W4[(size_t)(c0 + c) * 320 + (n0 + n) * 2 + half];
    }
    __syncthreads();
    const int b2 = t & 127, ch = t >> 7;
    v2f sacc[10] = {};
    for (int ci = 0; ci < 18; ++ci) {
        const int c = ch * 18 + ci;            // local 0..35
        v2f xk[8];
#pragma unroll
        for (int k = 0; k < 8; ++k)
            xk[k] = *reinterpret_cast<const v2f*>(
                Xt + (size_t)(k * C_IN + c0 + c) * B_SZ + 2 * b2);
#pragma unroll
        for (int n = 0; n < 10; ++n) {
            v2f acc = {0.f, 0.f};
            const float* wp = &Wl[(c * 10 + n) * 8];
#pragma unroll
            for (int k = 0; k < 8; ++k) {
                const float w = wp[k];
                acc += xk[k] * (v2f){w, w};    // v_pk_fma_f32
            }
            U2[((size_t)(n0 + n) * C_IN + c0 + c) * 128 + b2] =
                __floats2half2_rn(acc.x, acc.y);
            sacc[n] += acc;
        }
    }
#pragma unroll
    for (int n = 0; n < 10; ++n) Sred[ch][n][b2] = sacc[n];
    __syncthreads();
    for (int i = t; i < 1280; i += 256) {      // 10 n x 128 b-pairs
        const int n = i >> 7, bi = i & 127;
        const v2f s = Sred[0][n][bi] + Sred[1][n][bi];
        *reinterpret_cast<float2*>(
            s32 + ((size_t)cc * N_DIM + n0 + n) * B_SZ + 2 * bi) =
            make_float2(0.1f * s.x, 0.1f * s.y);
    }
}

// ================= gemvs: s[n][b] = sum_c csm[c,j(n)] * U[n][c][b] ===============
// 640 blocks = 8 c-eighths(144) x 80 n-pairs. nobij: b = agg only (it1, where
// b_prev == 0 mathematically). Thread = (b-pair, n-half).
__global__ __launch_bounds__(256) void k_gemvs(const __half2* __restrict__ U2,
                                               const float* __restrict__ bij_old,
                                               float* __restrict__ bij_new,
                                               const float* __restrict__ agg,
                                               float* __restrict__ s_part,
                                               int nobij) {
    __shared__ float braw[1440];
    __shared__ float csm[144];
    const int ce = blockIdx.x / 80, np = blockIdx.x % 80;
    const int c0 = ce * 144, n0 = np * 2, j = np >> 3;   // n-pair never crosses j
    const int t = threadIdx.x;
    for (int i = t; i < 1440; i += 256) {
        float v = agg[c0 * J_U + i];
        if (!nobij) v += bij_old[c0 * J_U + i];
        braw[i] = v;
        if (np == 0) bij_new[c0 * J_U + i] = v;   // duplicates benign
    }
    __syncthreads();
    for (int c = t; c < 144; c += 256) {
        const int r0 = c * J_U;
        float mx = -1e30f;
#pragma unroll
        for (int q = 0; q < J_U; ++q) mx = fmaxf(mx, braw[r0 + q]);
        float sum = 0.f;
#pragma unroll
        for (int q = 0; q < J_U; ++q) sum += __expf(braw[r0 + q] - mx);
        csm[c] = __expf(braw[r0 + j] - mx) / sum;
    }
    __syncthreads();
    const int b2 = t & 127, nh = t >> 7;
    const int nn = n0 + nh;
    const __half2* up = U2 + ((size_t)nn * C_IN + c0) * 128 + b2;
    v2f acc = {0.f, 0.f};
#pragma unroll 8
    for (int c = 0; c < 144; ++c) {
        const float2 f = __half22float2(up[(size_t)c * 128]);
        const float cs = csm[c];
        acc += (v2f){cs, cs} * (v2f){f.x, f.y};    // v_pk_fma_f32
    }
    *reinterpret_cast<float2*>(s_part + (size_t)ce * 40960 + (size_t)nn * B_SZ + 2 * b2) =
        make_float2(acc.x, acc.y);
}

// ================= agree: agg[c,j] = sum_{b,d} U[j*16+d][c][b] * v[b,d] =========
// 960 blocks = 10 j x 96 c-chunks(12), XCD-swizzled so j-siblings (sharing the
// s-read region) land on one XCD. Prologue: reduce nsl s-slices + squash
// (j-local) -> v in LDS. Main: thread = (b-pair, c-half).
__global__ __launch_bounds__(256) void k_agree(const __half2* __restrict__ U2,
                                               const float* __restrict__ s_base,
                                               int nsl,
                                               float* __restrict__ agg) {
    __shared__ float sv[16 * 256];                 // [d][b]: s then v in place
    __shared__ float red[12 * 128];
    const int vb = (blockIdx.x & 7) * 120 + (blockIdx.x >> 3);  // XCD swizzle (960=8x120)
    const int j = vb / 96, cc = vb % 96;
    const int c0 = cc * 12;
    const int t = threadIdx.x;
    for (int i = t; i < 4096; i += 256) {          // reduce slices, +1e-5 (ref order)
        const int d = i >> 8, b = i & 255;
        const float* p = s_base + (size_t)(j * 16 + d) * B_SZ + b;
        float s = 1e-5f;
#pragma unroll 8
        for (int ce = 0; ce < nsl; ++ce) s += p[(size_t)ce * 40960];
        sv[d * 256 + b] = s;
    }
    __syncthreads();
    {                                              // squash per b (t = b)
        float mag = 0.f;
#pragma unroll
        for (int d = 0; d < 16; ++d) { const float xx = sv[d * 256 + t]; mag += xx * xx; }
        const float sc = sqrtf(mag) / (1.f + mag);
#pragma unroll
        for (int d = 0; d < 16; ++d) sv[d * 256 + t] *= sc;
    }
    __syncthreads();
    const int b2 = t & 127, ch = t >> 7;
    float acc[6] = {};
#pragma unroll
    for (int ci = 0; ci < 6; ++ci) {
        const int c = c0 + ch * 6 + ci;
        const __half2* up = U2 + ((size_t)(j * 16) * C_IN + c) * 128 + b2;
#pragma unroll
        for (int d = 0; d < 16; ++d) {
            const float2 f = __half22float2(up[(size_t)d * C_IN * 128]);
            const float2 vv = *reinterpret_cast<const float2*>(&sv[d * 256 + 2 * b2]);
            acc[ci] += f.x * vv.x + f.y * vv.y;
        }
    }
#pragma unroll
    for (int ci = 0; ci < 6; ++ci) red[(ch * 6 + ci) * 128 + b2] = acc[ci];
    __syncthreads();
#pragma unroll
    for (int pass = 0; pass < 3; ++pass) {         // 12 rows x reduce-128
        const int r = pass * 4 + (t >> 6), l = t & 63;
        float v = red[r * 128 + l] + red[r * 128 + l + 64];
#pragma unroll
        for (int off = 32; off > 0; off >>= 1) v += __shfl_down(v, off);
        if (l == 0) agg[(size_t)(c0 + r) * J_U + j] = v;
    }
}

// ================= sqout: final squash s_part8 -> out =================
__global__ __launch_bounds__(256) void k_sqout(const float* __restrict__ s_part,
                                               float* __restrict__ out) {
    __shared__ float sl[16 * 32];
    const int j = blockIdx.x >> 3, bc = blockIdx.x & 7;
    const int b0 = bc * 32;
    const int t = threadIdx.x;
    for (int i = t; i < 512; i += 256) {
        const int d = i >> 5, bl = i & 31;
        const float* p = s_part + (size_t)(j * 16 + d) * B_SZ + b0 + bl;
        float s = 1e-5f;
#pragma unroll
        for (int ce = 0; ce < 8; ++ce) s += p[(size_t)ce * 40960];
        sl[d * 32 + bl] = s;
    }
    __syncthreads();
    if (t < 32) {
        float mag = 0.f;
#pragma unroll
        for (int d = 0; d < 16; ++d) { const float xx = sl[d * 32 + t]; mag += xx * xx; }
        const float sc = sqrtf(mag) / (1.f + mag);
#pragma unroll
        for (int d = 0; d < 16; ++d)
            out[(size_t)(b0 + t) * N_DIM + j * 16 + d] = sl[d * 32 + t] * sc;
    }
}

extern "C" void kernel_launch(void* const* d_in, const int* in_sizes, int n_in,
                              void* d_out, int out_size, void* d_ws, size_t ws_size,
                              hipStream_t stream) {
    const float* x = (const float*)d_in[0];   // (256, 8, 1152) fp32
    const float* W = (const float*)d_in[1];   // (1, 1152, 10, 16, 8) fp32
    float* out = (float*)d_out;               // (256, 10, 16, 1) fp32
    float* ws  = (float*)d_ws;
    float* Xt   = ws + OFF_XT;
    __half2* U2 = (__half2*)(ws + OFF_U);
    float* sp8  = ws + OFF_SP8;
    float* sp32 = ws + OFF_SP32;
    float* bij0 = ws + OFF_B0;
    float* bij1 = ws + OFF_B1;
    float* agg  = ws + OFF_AG;

    k_prep<<<576, 256, 0, stream>>>(x, Xt);
    k_ubuild<<<512, 256, 0, stream>>>(Xt, W, U2, sp32);       // U + s0 (csm=0.1)
    k_agree<<<960, 256, 0, stream>>>(U2, sp32, 32, agg);      // v0 -> agg0
    k_gemvs<<<640, 256, 0, stream>>>(U2, bij1, bij0, agg, sp8, 1);  // b1=agg0, s1
    k_agree<<<960, 256, 0, stream>>>(U2, sp8, 8, agg);        // v1 -> agg1
    k_gemvs<<<640, 256, 0, stream>>>(U2, bij0, bij1, agg, sp8, 0);  // b2, s2
    k_agree<<<960, 256, 0, stream>>>(U2, sp8, 8, agg);        // v2 -> agg2
    k_gemvs<<<640, 256, 0, stream>>>(U2, bij1, bij0, agg, sp8, 0);  // b3, s3 (bn dead)
    k_sqout<<<80, 256, 0, stream>>>(sp8, out);                // v3 -> out
}

// Round 13
// 214.157 us; speedup vs baseline: 1.1466x; 1.1466x over previous
//
#include <hip/hip_runtime.h>
#include <hip/hip_fp16.h>

// Capsule routing via materialized fp16 u_hat (L3-resident), multi-kernel,
// plain stores only. Ledger: R1 coop grid.sync ~60us -> never. R2 contended
// atomics -> never. R3/R4 occupancy juggling -> regress. R5 XCD swizzle (WR
// panel, shared dominant stream) +6.5us win. R8 fp16 split-K 254.7. R9 pk_fma
// 248.8. R11 materialized-U 216.7. R12 = fusion + agree/ubuild XCD swizzles =
// 245.5 REGRESS: agree's swizzle put each j's 9.4MB U-slab (>4MB L2) on ONE
// XCD -> 52us/dispatch at 12% HBM. Swizzle only when the DOMINANT stream is
// shared. R13 = R12 structure, linear block maps (R11 dispatch), nsl as
// compile-time template (full unroll).
// B=256, K_IN=8, C=1152, J=10, D=16, 4 iters. n = j*16+d.

typedef float v2f __attribute__((ext_vector_type(2)));

#define C_IN  1152
#define J_U   10
#define M_DIM 9216
#define N_DIM 160
#define B_SZ  256

// ---- ws layout (float offsets); ws is 256 MiB = 67.1M floats ----
#define OFF_XT  0              // Xt[9216][256] fp32
#define OFF_U   2400000        // U half[160][1152][256] = 23.6M floats of space
#define OFF_SP8 26000000       // s_part fp32 [8][160][256]
#define OFF_SP32 26400000      // s_part fp32 [32][160][256] (it0, from ubuild)
#define OFF_B0  27800000       // bij ping [1152][10]
#define OFF_B1  27820000       // bij pong [1152][10]
#define OFF_AG  27840000       // agg [1152][10] (full, written before read)

// ================= prep: transpose x -> Xt (proven 64x64 tile) =================
__global__ __launch_bounds__(256) void k_prep(const float* __restrict__ x,
                                              float* __restrict__ Xt) {
    __shared__ float T[64][65];
    const int bid = blockIdx.x, t = threadIdx.x;
    const int m0 = (bid % 144) * 64, b0 = (bid / 144) * 64;
    {
        const int b_l = t >> 2, q = t & 3;
        const float* xp = x + (size_t)(b0 + b_l) * M_DIM + m0 + q * 16;
#pragma unroll
        for (int u = 0; u < 4; ++u) {
            const float4 v = *reinterpret_cast<const float4*>(xp + 4 * u);
            T[q * 16 + 4 * u + 0][b_l] = v.x;
            T[q * 16 + 4 * u + 1][b_l] = v.y;
            T[q * 16 + 4 * u + 2][b_l] = v.z;
            T[q * 16 + 4 * u + 3][b_l] = v.w;
        }
    }
    __syncthreads();
    {
        const int m_l = t >> 2, q = t & 3;
        float4* op = reinterpret_cast<float4*>(Xt + (size_t)(m0 + m_l) * B_SZ + b0 + q * 16);
#pragma unroll
        for (int u = 0; u < 4; ++u)
            op[u] = make_float4(T[m_l][q * 16 + 4 * u], T[m_l][q * 16 + 4 * u + 1],
                                T[m_l][q * 16 + 4 * u + 2], T[m_l][q * 16 + 4 * u + 3]);
    }
}

// ===== ubuild: U[n][c][b] = sum_k W[c,n,k]*Xt[k*C+c][b]; also s0 split-K ========
// 512 blocks = 32 c-chunks(36) x 16 n-chunks(10), LINEAR mapping (nc-siblings
// round-robin across XCDs; 295KB x-slice duplicated per-XCD L2 -- cheap).
// Epilogue: s0[cc][n][b] = 0.1 * sum over the block's 36 c (csm==0.1 at it0).
__global__ __launch_bounds__(256) void k_ubuild(const float* __restrict__ Xt,
                                                const float* __restrict__ W,
                                                __half2* __restrict__ U2,
                                                float* __restrict__ s32) {
    __shared__ float Wl[2880];                 // [36 c][10 n][8 k]
    __shared__ v2f Sred[2][10][128];
    const int cc = blockIdx.x >> 4, nc = blockIdx.x & 15;
    const int c0 = cc * 36, n0 = nc * 10;
    const int t = threadIdx.x;
    const float4* W4 = reinterpret_cast<const float4*>(W);
    float4* Wl4 = reinterpret_cast<float4*>(Wl);
    for (int i = t; i < 720; i += 256) {       // 36 c x 10 n x 2 float4
        const int c = i / 20, r = i - c * 20;
        const int n = r >> 1, half = r & 1;
        Wl4[i] = W4[(size_t)(c0 + c) * 320 + (n0 + n) * 2 + half];
    }
    __syncthreads();
    const int b2 = t & 127, ch = t >> 7;
    v2f sacc[10] = {};
    for (int ci = 0; ci < 18; ++ci) {
        const int c = ch * 18 + ci;            // local 0..35
        v2f xk[8];
#pragma unroll
        for (int k = 0; k < 8; ++k)
            xk[k] = *reinterpret_cast<const v2f*>(
                Xt + (size_t)(k * C_IN + c0 + c) * B_SZ + 2 * b2);
#pragma unroll
        for (int n = 0; n < 10; ++n) {
            v2f acc = {0.f, 0.f};
            const float* wp = &Wl[(c * 10 + n) * 8];
#pragma unroll
            for (int k = 0; k < 8; ++k) {
                const float w = wp[k];
                acc += xk[k] * (v2f){w, w};    // v_pk_fma_f32
            }
            U2[((size_t)(n0 + n) * C_IN + c0 + c) * 128 + b2] =
                __floats2half2_rn(acc.x, acc.y);
            sacc[n] += acc;
        }
    }
#pragma unroll
    for (int n = 0; n < 10; ++n) Sred[ch][n][b2] = sacc[n];
    __syncthreads();
    for (int i = t; i < 1280; i += 256) {      // 10 n x 128 b-pairs
        const int n = i >> 7, bi = i & 127;
        const v2f s = Sred[0][n][bi] + Sred[1][n][bi];
        *reinterpret_cast<float2*>(
            s32 + ((size_t)cc * N_DIM + n0 + n) * B_SZ + 2 * bi) =
            make_float2(0.1f * s.x, 0.1f * s.y);
    }
}

// ================= gemvs: s[n][b] = sum_c csm[c,j(n)] * U[n][c][b] ===============
// 640 blocks = 8 c-eighths(144) x 80 n-pairs. nobij: b = agg only (it1, where
// b_prev == 0 mathematically). Thread = (b-pair, n-half).
__global__ __launch_bounds__(256) void k_gemvs(const __half2* __restrict__ U2,
                                               const float* __restrict__ bij_old,
                                               float* __restrict__ bij_new,
                                               const float* __restrict__ agg,
                                               float* __restrict__ s_part,
                                               int nobij) {
    __shared__ float braw[1440];
    __shared__ float csm[144];
    const int ce = blockIdx.x / 80, np = blockIdx.x % 80;
    const int c0 = ce * 144, n0 = np * 2, j = np >> 3;   // n-pair never crosses j
    const int t = threadIdx.x;
    for (int i = t; i < 1440; i += 256) {
        float v = agg[c0 * J_U + i];
        if (!nobij) v += bij_old[c0 * J_U + i];
        braw[i] = v;
        if (np == 0) bij_new[c0 * J_U + i] = v;   // duplicates benign
    }
    __syncthreads();
    for (int c = t; c < 144; c += 256) {
        const int r0 = c * J_U;
        float mx = -1e30f;
#pragma unroll
        for (int q = 0; q < J_U; ++q) mx = fmaxf(mx, braw[r0 + q]);
        float sum = 0.f;
#pragma unroll
        for (int q = 0; q < J_U; ++q) sum += __expf(braw[r0 + q] - mx);
        csm[c] = __expf(braw[r0 + j] - mx) / sum;
    }
    __syncthreads();
    const int b2 = t & 127, nh = t >> 7;
    const int nn = n0 + nh;
    const __half2* up = U2 + ((size_t)nn * C_IN + c0) * 128 + b2;
    v2f acc = {0.f, 0.f};
#pragma unroll 8
    for (int c = 0; c < 144; ++c) {
        const float2 f = __half22float2(up[(size_t)c * 128]);
        const float cs = csm[c];
        acc += (v2f){cs, cs} * (v2f){f.x, f.y};    // v_pk_fma_f32
    }
    *reinterpret_cast<float2*>(s_part + (size_t)ce * 40960 + (size_t)nn * B_SZ + 2 * b2) =
        make_float2(acc.x, acc.y);
}

// ================= agree: agg[c,j] = sum_{b,d} U[j*16+d][c][b] * v[b,d] =========
// 960 blocks = 10 j x 96 c-chunks(12), LINEAR mapping (R11 dispatch: each j's
// 9.4MB U-slab spreads across all 8 XCDs). NSL compile-time -> full unroll.
template <int NSL>
__global__ __launch_bounds__(256) void k_agree(const __half2* __restrict__ U2,
                                               const float* __restrict__ s_base,
                                               float* __restrict__ agg) {
    __shared__ float sv[16 * 256];                 // [d][b]: s then v in place
    __shared__ float red[12 * 128];
    const int j = blockIdx.x / 96, cc = blockIdx.x % 96;
    const int c0 = cc * 12;
    const int t = threadIdx.x;
    for (int i = t; i < 4096; i += 256) {          // reduce slices, +1e-5 (ref order)
        const int d = i >> 8, b = i & 255;
        const float* p = s_base + (size_t)(j * 16 + d) * B_SZ + b;
        float s = 1e-5f;
#pragma unroll
        for (int ce = 0; ce < NSL; ++ce) s += p[(size_t)ce * 40960];
        sv[d * 256 + b] = s;
    }
    __syncthreads();
    {                                              // squash per b (t = b)
        float mag = 0.f;
#pragma unroll
        for (int d = 0; d < 16; ++d) { const float xx = sv[d * 256 + t]; mag += xx * xx; }
        const float sc = sqrtf(mag) / (1.f + mag);
#pragma unroll
        for (int d = 0; d < 16; ++d) sv[d * 256 + t] *= sc;
    }
    __syncthreads();
    const int b2 = t & 127, ch = t >> 7;
    float acc[6] = {};
#pragma unroll
    for (int ci = 0; ci < 6; ++ci) {
        const int c = c0 + ch * 6 + ci;
        const __half2* up = U2 + ((size_t)(j * 16) * C_IN + c) * 128 + b2;
#pragma unroll
        for (int d = 0; d < 16; ++d) {
            const float2 f = __half22float2(up[(size_t)d * C_IN * 128]);
            const float2 vv = *reinterpret_cast<const float2*>(&sv[d * 256 + 2 * b2]);
            acc[ci] += f.x * vv.x + f.y * vv.y;
        }
    }
#pragma unroll
    for (int ci = 0; ci < 6; ++ci) red[(ch * 6 + ci) * 128 + b2] = acc[ci];
    __syncthreads();
#pragma unroll
    for (int pass = 0; pass < 3; ++pass) {         // 12 rows x reduce-128
        const int r = pass * 4 + (t >> 6), l = t & 63;
        float v = red[r * 128 + l] + red[r * 128 + l + 64];
#pragma unroll
        for (int off = 32; off > 0; off >>= 1) v += __shfl_down(v, off);
        if (l == 0) agg[(size_t)(c0 + r) * J_U + j] = v;
    }
}

// ================= sqout: final squash s_part8 -> out =================
__global__ __launch_bounds__(256) void k_sqout(const float* __restrict__ s_part,
                                               float* __restrict__ out) {
    __shared__ float sl[16 * 32];
    const int j = blockIdx.x >> 3, bc = blockIdx.x & 7;
    const int b0 = bc * 32;
    const int t = threadIdx.x;
    for (int i = t; i < 512; i += 256) {
        const int d = i >> 5, bl = i & 31;
        const float* p = s_part + (size_t)(j * 16 + d) * B_SZ + b0 + bl;
        float s = 1e-5f;
#pragma unroll
        for (int ce = 0; ce < 8; ++ce) s += p[(size_t)ce * 40960];
        sl[d * 32 + bl] = s;
    }
    __syncthreads();
    if (t < 32) {
        float mag = 0.f;
#pragma unroll
        for (int d = 0; d < 16; ++d) { const float xx = sl[d * 32 + t]; mag += xx * xx; }
        const float sc = sqrtf(mag) / (1.f + mag);
#pragma unroll
        for (int d = 0; d < 16; ++d)
            out[(size_t)(b0 + t) * N_DIM + j * 16 + d] = sl[d * 32 + t] * sc;
    }
}

extern "C" void kernel_launch(void* const* d_in, const int* in_sizes, int n_in,
                              void* d_out, int out_size, void* d_ws, size_t ws_size,
                              hipStream_t stream) {
    const float* x = (const float*)d_in[0];   // (256, 8, 1152) fp32
    const float* W = (const float*)d_in[1];   // (1, 1152, 10, 16, 8) fp32
    float* out = (float*)d_out;               // (256, 10, 16, 1) fp32
    float* ws  = (float*)d_ws;
    float* Xt   = ws + OFF_XT;
    __half2* U2 = (__half2*)(ws + OFF_U);
    float* sp8  = ws + OFF_SP8;
    float* sp32 = ws + OFF_SP32;
    float* bij0 = ws + OFF_B0;
    float* bij1 = ws + OFF_B1;
    float* agg  = ws + OFF_AG;

    k_prep<<<576, 256, 0, stream>>>(x, Xt);
    k_ubuild<<<512, 256, 0, stream>>>(Xt, W, U2, sp32);            // U + s0 (csm=0.1)
    k_agree<32><<<960, 256, 0, stream>>>(U2, sp32, agg);           // v0 -> agg0
    k_gemvs<<<640, 256, 0, stream>>>(U2, bij1, bij0, agg, sp8, 1); // b1=agg0, s1
    k_agree<8><<<960, 256, 0, stream>>>(U2, sp8, agg);             // v1 -> agg1
    k_gemvs<<<640, 256, 0, stream>>>(U2, bij0, bij1, agg, sp8, 0); // b2, s2
    k_agree<8><<<960, 256, 0, stream>>>(U2, sp8, agg);             // v2 -> agg2
    k_gemvs<<<640, 256, 0, stream>>>(U2, bij1, bij0, agg, sp8, 0); // b3, s3 (bn dead)
    k_sqout<<<80, 256, 0, stream>>>(sp8, out);                     // v3 -> out
}

// Round 14
// 213.259 us; speedup vs baseline: 1.1514x; 1.0042x over previous
//
#include <hip/hip_runtime.h>
#include <hip/hip_fp16.h>

// Capsule routing via materialized fp16 u_hat (L3-resident), multi-kernel,
// plain stores only. Ledger: R1 coop grid.sync ~60us -> never. R2 contended
// atomics -> never. R3/R4 occupancy juggling -> regress. R5 XCD swizzle helps
// ONLY when the dominant stream is shared (R12: swizzling agree funneled each
// j's 9.4MB U-slab through one XCD L2 -> 52us, regress). R8 fp16 split-K.
// R9 pk_fma. R11 materialized-U 216.7. R13 fusion + linear maps = 214.2 (best).
// R14: c-pair-interleaved U layout U[n][c/2][b2][c&1] as uint2 -> 8B/lane loads
// on every U pass (gemvs 144->72 loads/thread, agree 96->48, ubuild 8B stores).
// Identical arithmetic; only packing order changes.
// B=256, K_IN=8, C=1152, J=10, D=16, 4 iters. n = j*16+d.

typedef float v2f __attribute__((ext_vector_type(2)));

#define C_IN  1152
#define J_U   10
#define M_DIM 9216
#define N_DIM 160
#define B_SZ  256

// ---- ws layout (float offsets); ws is 256 MiB = 67.1M floats ----
#define OFF_XT  0              // Xt[9216][256] fp32
#define OFF_U   2400000        // U uint2[160][576][128] = 94 MB
#define OFF_SP8 26000000       // s_part fp32 [8][160][256]
#define OFF_SP32 26400000      // s_part fp32 [32][160][256] (it0, from ubuild)
#define OFF_B0  27800000       // bij ping [1152][10]
#define OFF_B1  27820000       // bij pong [1152][10]
#define OFF_AG  27840000       // agg [1152][10] (full, written before read)

// ================= prep: transpose x -> Xt (proven 64x64 tile) =================
__global__ __launch_bounds__(256) void k_prep(const float* __restrict__ x,
                                              float* __restrict__ Xt) {
    __shared__ float T[64][65];
    const int bid = blockIdx.x, t = threadIdx.x;
    const int m0 = (bid % 144) * 64, b0 = (bid / 144) * 64;
    {
        const int b_l = t >> 2, q = t & 3;
        const float* xp = x + (size_t)(b0 + b_l) * M_DIM + m0 + q * 16;
#pragma unroll
        for (int u = 0; u < 4; ++u) {
            const float4 v = *reinterpret_cast<const float4*>(xp + 4 * u);
            T[q * 16 + 4 * u + 0][b_l] = v.x;
            T[q * 16 + 4 * u + 1][b_l] = v.y;
            T[q * 16 + 4 * u + 2][b_l] = v.z;
            T[q * 16 + 4 * u + 3][b_l] = v.w;
        }
    }
    __syncthreads();
    {
        const int m_l = t >> 2, q = t & 3;
        float4* op = reinterpret_cast<float4*>(Xt + (size_t)(m0 + m_l) * B_SZ + b0 + q * 16);
#pragma unroll
        for (int u = 0; u < 4; ++u)
            op[u] = make_float4(T[m_l][q * 16 + 4 * u], T[m_l][q * 16 + 4 * u + 1],
                                T[m_l][q * 16 + 4 * u + 2], T[m_l][q * 16 + 4 * u + 3]);
    }
}

// ===== ubuild: U[n][cp][b2] (c-pair uint2) = sum_k W*Xt; also s0 split-K ========
// 512 blocks = 32 c-chunks(36) x 16 n-chunks(10), LINEAR mapping.
// Thread processes c-pairs (xa/xb streams); stores 8B per (n, c-pair).
// Epilogue: s0[cc][n][b] = 0.1 * sum over the block's 36 c (csm==0.1 at it0).
__global__ __launch_bounds__(256) void k_ubuild(const float* __restrict__ Xt,
                                                const float* __restrict__ W,
                                                uint2* __restrict__ U4,
                                                float* __restrict__ s32) {
    __shared__ float Wl[2880];                 // [36 c][10 n][8 k]
    __shared__ v2f Sred[2][10][128];
    const int cc = blockIdx.x >> 4, nc = blockIdx.x & 15;
    const int c0 = cc * 36, n0 = nc * 10;
    const int t = threadIdx.x;
    const float4* W4 = reinterpret_cast<const float4*>(W);
    float4* Wl4 = reinterpret_cast<float4*>(Wl);
    for (int i = t; i < 720; i += 256) {       // 36 c x 10 n x 2 float4
        const int c = i / 20, r = i - c * 20;
        const int n = r >> 1, half = r & 1;
        Wl4[i] = W4[(size_t)(c0 + c) * 320 + (n0 + n) * 2 + half];
    }
    __syncthreads();
    const int b2 = t & 127, ch = t >> 7;
    v2f sacc[10] = {};
    for (int cp = 0; cp < 9; ++cp) {
        const int ca = ch * 18 + 2 * cp;       // local c (even)
        v2f xa[8], xb[8];
#pragma unroll
        for (int k = 0; k < 8; ++k) {
            xa[k] = *reinterpret_cast<const v2f*>(
                Xt + (size_t)(k * C_IN + c0 + ca) * B_SZ + 2 * b2);
            xb[k] = *reinterpret_cast<const v2f*>(
                Xt + (size_t)(k * C_IN + c0 + ca + 1) * B_SZ + 2 * b2);
        }
        const int cpg = (c0 + ca) >> 1;        // global c-pair index
#pragma unroll
        for (int n = 0; n < 10; ++n) {
            v2f acca = {0.f, 0.f}, accb = {0.f, 0.f};
            const float* wa = &Wl[(ca * 10 + n) * 8];
            const float* wb = &Wl[((ca + 1) * 10 + n) * 8];
#pragma unroll
            for (int k = 0; k < 8; ++k) {
                acca += xa[k] * (v2f){wa[k], wa[k]};   // v_pk_fma_f32
                accb += xb[k] * (v2f){wb[k], wb[k]};
            }
            const __half2 ha = __floats2half2_rn(acca.x, acca.y);
            const __half2 hb = __floats2half2_rn(accb.x, accb.y);
            uint2 st;
            st.x = *reinterpret_cast<const unsigned*>(&ha);
            st.y = *reinterpret_cast<const unsigned*>(&hb);
            U4[((size_t)(n0 + n) * 576 + cpg) * 128 + b2] = st;
            sacc[n] += acca + accb;
        }
    }
#pragma unroll
    for (int n = 0; n < 10; ++n) Sred[ch][n][b2] = sacc[n];
    __syncthreads();
    for (int i = t; i < 1280; i += 256) {      // 10 n x 128 b-pairs
        const int n = i >> 7, bi = i & 127;
        const v2f s = Sred[0][n][bi] + Sred[1][n][bi];
        *reinterpret_cast<float2*>(
            s32 + ((size_t)cc * N_DIM + n0 + n) * B_SZ + 2 * bi) =
            make_float2(0.1f * s.x, 0.1f * s.y);
    }
}

// ================= gemvs: s[n][b] = sum_c csm[c,j(n)] * U[n][c][b] ===============
// 640 blocks = 8 c-eighths(144) x 80 n-pairs. nobij: b = agg only (it1).
// Thread = (b-pair, n-half); 72 x 8B c-pair loads.
__global__ __launch_bounds__(256) void k_gemvs(const uint2* __restrict__ U4,
                                               const float* __restrict__ bij_old,
                                               float* __restrict__ bij_new,
                                               const float* __restrict__ agg,
                                               float* __restrict__ s_part,
                                               int nobij) {
    __shared__ float braw[1440];
    __shared__ float csm[144];
    const int ce = blockIdx.x / 80, np = blockIdx.x % 80;
    const int c0 = ce * 144, n0 = np * 2, j = np >> 3;   // n-pair never crosses j
    const int t = threadIdx.x;
    for (int i = t; i < 1440; i += 256) {
        float v = agg[c0 * J_U + i];
        if (!nobij) v += bij_old[c0 * J_U + i];
        braw[i] = v;
        if (np == 0) bij_new[c0 * J_U + i] = v;   // duplicates benign
    }
    __syncthreads();
    for (int c = t; c < 144; c += 256) {
        const int r0 = c * J_U;
        float mx = -1e30f;
#pragma unroll
        for (int q = 0; q < J_U; ++q) mx = fmaxf(mx, braw[r0 + q]);
        float sum = 0.f;
#pragma unroll
        for (int q = 0; q < J_U; ++q) sum += __expf(braw[r0 + q] - mx);
        csm[c] = __expf(braw[r0 + j] - mx) / sum;
    }
    __syncthreads();
    const int b2 = t & 127, nh = t >> 7;
    const int nn = n0 + nh;
    const uint2* up = U4 + ((size_t)nn * 576 + ce * 72) * 128 + b2;
    v2f acc = {0.f, 0.f};
#pragma unroll 8
    for (int cp = 0; cp < 72; ++cp) {
        const uint2 u = up[(size_t)cp * 128];
        const float2 fa = __half22float2(reinterpret_cast<const __half2&>(u.x));
        const float2 fb = __half22float2(reinterpret_cast<const __half2&>(u.y));
        const float ca_ = csm[2 * cp], cb_ = csm[2 * cp + 1];
        acc += (v2f){ca_, ca_} * (v2f){fa.x, fa.y};    // v_pk_fma_f32
        acc += (v2f){cb_, cb_} * (v2f){fb.x, fb.y};
    }
    *reinterpret_cast<float2*>(s_part + (size_t)ce * 40960 + (size_t)nn * B_SZ + 2 * b2) =
        make_float2(acc.x, acc.y);
}

// ================= agree: agg[c,j] = sum_{b,d} U[j*16+d][c][b] * v[b,d] =========
// 960 blocks = 10 j x 96 c-chunks(12), LINEAR mapping. NSL compile-time.
// Thread = (b-pair, c-half); 3 c-pairs x 16 d x 8B loads.
template <int NSL>
__global__ __launch_bounds__(256) void k_agree(const uint2* __restrict__ U4,
                                               const float* __restrict__ s_base,
                                               float* __restrict__ agg) {
    __shared__ float sv[16 * 256];                 // [d][b]: s then v in place
    __shared__ float red[12 * 128];
    const int j = blockIdx.x / 96, cc = blockIdx.x % 96;
    const int c0 = cc * 12;
    const int t = threadIdx.x;
    for (int i = t; i < 4096; i += 256) {          // reduce slices, +1e-5 (ref order)
        const int d = i >> 8, b = i & 255;
        const float* p = s_base + (size_t)(j * 16 + d) * B_SZ + b;
        float s = 1e-5f;
#pragma unroll
        for (int ce = 0; ce < NSL; ++ce) s += p[(size_t)ce * 40960];
        sv[d * 256 + b] = s;
    }
    __syncthreads();
    {                                              // squash per b (t = b)
        float mag = 0.f;
#pragma unroll
        for (int d = 0; d < 16; ++d) { const float xx = sv[d * 256 + t]; mag += xx * xx; }
        const float sc = sqrtf(mag) / (1.f + mag);
#pragma unroll
        for (int d = 0; d < 16; ++d) sv[d * 256 + t] *= sc;
    }
    __syncthreads();
    const int b2 = t & 127, ch = t >> 7;
    float acc[6] = {};
#pragma unroll
    for (int cp = 0; cp < 3; ++cp) {
        const int cpg = (c0 >> 1) + ch * 3 + cp;   // global c-pair index
        const uint2* up = U4 + ((size_t)(j * 16) * 576 + cpg) * 128 + b2;
#pragma unroll
        for (int d = 0; d < 16; ++d) {
            const uint2 u = up[(size_t)d * 576 * 128];
            const float2 fa = __half22float2(reinterpret_cast<const __half2&>(u.x));
            const float2 fb = __half22float2(reinterpret_cast<const __half2&>(u.y));
            const float2 vv = *reinterpret_cast<const float2*>(&sv[d * 256 + 2 * b2]);
            acc[2 * cp]     += fa.x * vv.x + fa.y * vv.y;
            acc[2 * cp + 1] += fb.x * vv.x + fb.y * vv.y;
        }
    }
#pragma unroll
    for (int ci = 0; ci < 6; ++ci) red[(ch * 6 + ci) * 128 + b2] = acc[ci];
    __syncthreads();
#pragma unroll
    for (int pass = 0; pass < 3; ++pass) {         // 12 rows x reduce-128
        const int r = pass * 4 + (t >> 6), l = t & 63;
        float v = red[r * 128 + l] + red[r * 128 + l + 64];
#pragma unroll
        for (int off = 32; off > 0; off >>= 1) v += __shfl_down(v, off);
        if (l == 0) agg[(size_t)(c0 + r) * J_U + j] = v;
    }
}

// ================= sqout: final squash s_part8 -> out =================
__global__ __launch_bounds__(256) void k_sqout(const float* __restrict__ s_part,
                                               float* __restrict__ out) {
    __shared__ float sl[16 * 32];
    const int j = blockIdx.x >> 3, bc = blockIdx.x & 7;
    const int b0 = bc * 32;
    const int t = threadIdx.x;
    for (int i = t; i < 512; i += 256) {
        const int d = i >> 5, bl = i & 31;
        const float* p = s_part + (size_t)(j * 16 + d) * B_SZ + b0 + bl;
        float s = 1e-5f;
#pragma unroll
        for (int ce = 0; ce < 8; ++ce) s += p[(size_t)ce * 40960];
        sl[d * 32 + bl] = s;
    }
    __syncthreads();
    if (t < 32) {
        float mag = 0.f;
#pragma unroll
        for (int d = 0; d < 16; ++d) { const float xx = sl[d * 32 + t]; mag += xx * xx; }
        const float sc = sqrtf(mag) / (1.f + mag);
#pragma unroll
        for (int d = 0; d < 16; ++d)
            out[(size_t)(b0 + t) * N_DIM + j * 16 + d] = sl[d * 32 + t] * sc;
    }
}

extern "C" void kernel_launch(void* const* d_in, const int* in_sizes, int n_in,
                              void* d_out, int out_size, void* d_ws, size_t ws_size,
                              hipStream_t stream) {
    const float* x = (const float*)d_in[0];   // (256, 8, 1152) fp32
    const float* W = (const float*)d_in[1];   // (1, 1152, 10, 16, 8) fp32
    float* out = (float*)d_out;               // (256, 10, 16, 1) fp32
    float* ws  = (float*)d_ws;
    float* Xt   = ws + OFF_XT;
    uint2* U4   = (uint2*)(ws + OFF_U);
    float* sp8  = ws + OFF_SP8;
    float* sp32 = ws + OFF_SP32;
    float* bij0 = ws + OFF_B0;
    float* bij1 = ws + OFF_B1;
    float* agg  = ws + OFF_AG;

    k_prep<<<576, 256, 0, stream>>>(x, Xt);
    k_ubuild<<<512, 256, 0, stream>>>(Xt, W, U4, sp32);            // U + s0 (csm=0.1)
    k_agree<32><<<960, 256, 0, stream>>>(U4, sp32, agg);           // v0 -> agg0
    k_gemvs<<<640, 256, 0, stream>>>(U4, bij1, bij0, agg, sp8, 1); // b1=agg0, s1
    k_agree<8><<<960, 256, 0, stream>>>(U4, sp8, agg);             // v1 -> agg1
    k_gemvs<<<640, 256, 0, stream>>>(U4, bij0, bij1, agg, sp8, 0); // b2, s2
    k_agree<8><<<960, 256, 0, stream>>>(U4, sp8, agg);             // v2 -> agg2
    k_gemvs<<<640, 256, 0, stream>>>(U4, bij1, bij0, agg, sp8, 0); // b3, s3 (bn dead)
    k_sqout<<<80, 256, 0, stream>>>(sp8, out);                     // v3 -> out
}